// Round 5
// baseline (8050.232 us; speedup 1.0000x reference)
//
#include <hip/hip_runtime.h>
#include <math.h>

#define BSZ 64
#define PLEN 128
#define HLEN 64
#define EDIM 300
#define HDIM 512
#define G4 2048   // 4*HDIM
#define NCLS 3

__device__ __forceinline__ float sigf(float x) { return 1.0f / (1.0f + __expf(-x)); }
__device__ __forceinline__ float tanhfast(float x) { return 1.0f - 2.0f / (__expf(2.0f * x) + 1.0f); }

// LLC-coherent relaxed agent-scope atomics (bypass non-coherent XCD L2)
__device__ __forceinline__ unsigned long long aload64(const unsigned long long* p) {
    return __hip_atomic_load(p, __ATOMIC_RELAXED, __HIP_MEMORY_SCOPE_AGENT);
}
__device__ __forceinline__ void astore64(unsigned long long* p, unsigned long long v) {
    __hip_atomic_store(p, v, __ATOMIC_RELAXED, __HIP_MEMORY_SCOPE_AGENT);
}
__device__ __forceinline__ float aload32f(const float* p) {
    return __hip_atomic_load(p, __ATOMIC_RELAXED, __HIP_MEMORY_SCOPE_AGENT);
}
__device__ __forceinline__ void astore32f(float* p, float v) {
    __hip_atomic_store(p, v, __ATOMIC_RELAXED, __HIP_MEMORY_SCOPE_AGENT);
}
__device__ __forceinline__ unsigned aload32u(const unsigned* p) {
    return __hip_atomic_load(p, __ATOMIC_RELAXED, __HIP_MEMORY_SCOPE_AGENT);
}

// flag protocol: producer side (drain stores, block barrier, one inc)
__device__ __forceinline__ void postflag(unsigned* f) {
    __asm__ volatile("" ::: "memory");
    __builtin_amdgcn_s_waitcnt(0);
    __syncthreads();
    if (threadIdx.x == 0)
        __hip_atomic_fetch_add(f, 1u, __ATOMIC_RELAXED, __HIP_MEMORY_SCOPE_AGENT);
}
// consumer side
__device__ __forceinline__ void waitflag(unsigned* f, unsigned tgt) {
    if (threadIdx.x == 0) {
        while (aload32u(f) != tgt) __builtin_amdgcn_s_sleep(1);
    }
    __syncthreads();
    __asm__ volatile("" ::: "memory");
}

__global__ __launch_bounds__(256) void zero_u32(unsigned* p, int n) {
    int i = blockIdx.x * 256 + threadIdx.x;
    if (i < n) p[i] = 0u;
}

// ---------------------------------------------------------------------------
// input projection GEMM: out[m][row] = emb[toks[m]] . Wih[row] + bih[row]+bhh[row]
__global__ __launch_bounds__(256) void proj_kernel(
    const int* __restrict__ toks, const float* __restrict__ emb,
    const float* __restrict__ Wih, const float* __restrict__ bih,
    const float* __restrict__ bhh, float* __restrict__ out)
{
    __shared__ float es[16][EDIM];
    __shared__ float wsh[32][EDIM];
    int m0 = blockIdx.x * 16, r0 = blockIdx.y * 32;
    int tid = threadIdx.x;
    for (int i = tid; i < 16 * 75; i += 256) {
        int tk = i / 75, k4 = i % 75;
        ((float4*)&es[tk][0])[k4] = ((const float4*)(emb + (size_t)toks[m0 + tk] * EDIM))[k4];
    }
    for (int i = tid; i < 32 * 75; i += 256) {
        int r = i / 75, k4 = i % 75;
        ((float4*)&wsh[r][0])[k4] = ((const float4*)(Wih + (size_t)(r0 + r) * EDIM))[k4];
    }
    __syncthreads();
    int tx = tid & 31, ty = tid >> 5;
    const float4* w4 = (const float4*)&wsh[tx][0];
    const float4* e0 = (const float4*)&es[ty][0];
    const float4* e1 = (const float4*)&es[ty + 8][0];
    float a0 = 0.f, a1 = 0.f;
#pragma unroll 5
    for (int k = 0; k < 75; k++) {
        float4 w = w4[k];
        float4 x = e0[k]; a0 += x.x * w.x + x.y * w.y + x.z * w.z + x.w * w.w;
        float4 y = e1[k]; a1 += y.x * w.x + y.y * w.y + y.z * w.z + y.w * w.w;
    }
    float bsum = bih[r0 + tx] + bhh[r0 + tx];
    out[(size_t)(m0 + ty) * G4 + r0 + tx]     = a0 + bsum;
    out[(size_t)(m0 + ty + 8) * G4 + r0 + tx] = a1 + bsum;
}

// ---------------------------------------------------------------------------
// generic 16x16-tile GEMM: out[m][n] = sum_k A[m][k] * W[n][k], K = 512
__global__ __launch_bounds__(256) void gemm16(
    const float* __restrict__ A, const float* __restrict__ W,
    float* __restrict__ out)
{
    __shared__ float as[16][260];
    __shared__ float wsh2[16][260];
    int m0 = blockIdx.x * 16, n0 = blockIdx.y * 16;
    int tid = threadIdx.x, tx = tid & 15, ty = tid >> 4;
    float acc = 0.f;
    for (int kc = 0; kc < 2; kc++) {
        __syncthreads();
        for (int i = tid; i < 16 * 64; i += 256) {
            int row = i >> 6, k4 = i & 63;
            ((float4*)&as[row][0])[k4] =
                ((const float4*)(A + (size_t)(m0 + row) * HDIM + kc * 256))[k4];
            ((float4*)&wsh2[row][0])[k4] =
                ((const float4*)(W + (size_t)(n0 + row) * HDIM + kc * 256))[k4];
        }
        __syncthreads();
        const float4* av = (const float4*)&as[ty][0];
        const float4* wv4 = (const float4*)&wsh2[tx][0];
#pragma unroll 8
        for (int k = 0; k < 64; k++) {
            float4 a = av[k], ww = wv4[k];
            acc += a.x * ww.x + a.y * ww.y + a.z * ww.z + a.w * ww.w;
        }
    }
    out[(size_t)(m0 + ty) * HDIM + n0 + tx] = acc;
}

// ---------------------------------------------------------------------------
// persistent LSTM. 256 blocks = (ug 0..31, bg 0..7): 16 units, 8 batches.
// lane = gate-row (64), wave = k-chunk (4): pure-broadcast LDS GEMV reads.
__global__ __launch_bounds__(256, 1) void lstm_coop(
    const float* __restrict__ xp, const float* __restrict__ xh,
    const float* __restrict__ Whh1, const float* __restrict__ Whh2,
    float* __restrict__ outp, float* __restrict__ outh,
    float* __restrict__ hA, float* __restrict__ hB,
    unsigned* __restrict__ flags)
{
    const int tid = threadIdx.x;
    const int ug = blockIdx.x & 31;
    const int bg = blockIdx.x >> 5;
    const int u0 = ug * 16, b0 = bg * 8;
    const int r = tid & 63;       // gate-row: g = r>>4, unit = r&15
    const int c = tid >> 6;       // k-chunk (wave index)
    const int g = r >> 4, uu = r & 15;

    __shared__ float hst[8][528];     // chunk-padded: chunk c at offset c*132
    __shared__ float gsm[4][64][9];

    float4 w[32];
    {
        const float4* src = (const float4*)(Whh1 + (size_t)(g * HDIM + u0 + uu) * HDIM) + c * 32;
#pragma unroll
        for (int k = 0; k < 32; k++) w[k] = src[k];
    }
    float creg = 0.0f;
    const int bbc = tid >> 4, uuc = tid & 15;
    unsigned* myflags = flags + bg * 192;

    for (int t = 0; t < PLEN + HLEN; t++) {
        const int layer2 = (t >= PLEN) ? 1 : 0;
        const int tloc = layer2 ? t - PLEN : t;
        const int T = layer2 ? HLEN : PLEN;
        const float* xproj = layer2 ? xh : xp;
        float* outseq = layer2 ? outh : outp;
        float* hwr = (t & 1) ? hB : hA;
        const float* hrd = (t & 1) ? hA : hB;

        if (t == PLEN) {
            const float4* src = (const float4*)(Whh2 + (size_t)(g * HDIM + u0 + uu) * HDIM) + c * 32;
#pragma unroll
            for (int k = 0; k < 32; k++) w[k] = src[k];
        }
        // prefetch xproj gates (independent of h) before the flag wait
        float gi = 0.f, gf = 0.f, gg2 = 0.f, go = 0.f;
        if (tid < 128) {
            size_t xb = ((size_t)(b0 + bbc) * T + tloc) * G4 + u0 + uuc;
            gi = xproj[xb]; gf = xproj[xb + 512];
            gg2 = xproj[xb + 1024]; go = xproj[xb + 1536];
        }
        const bool have_h = (tloc != 0);
        if (have_h) {
            if (tid == 0) {
                while (aload32u(&myflags[t - 1]) != 32u) __builtin_amdgcn_s_sleep(1);
            }
            __syncthreads();
            __asm__ volatile("" ::: "memory");
            // stage h (8 b x 512) into padded LDS via LLC-coherent loads
            const unsigned long long* hs64 =
                (const unsigned long long*)hrd + (size_t)b0 * 256;
#pragma unroll
            for (int i = 0; i < 8; i++) {
                int idx = tid + i * 256;
                int bb = idx >> 8, j = idx & 255;
                unsigned long long v = aload64(hs64 + bb * 256 + j);
                int e = j * 2;
                *(unsigned long long*)&hst[bb][e + ((e >> 7) << 2)] = v;
            }
            __syncthreads();
            // GEMV: all 64 lanes read the SAME hst address -> pure broadcast
#pragma unroll 1
            for (int bb = 0; bb < 8; bb++) {
                const float4* hv = (const float4*)&hst[bb][c * 132];
                float ax = 0.f, ay = 0.f, az = 0.f, aw2 = 0.f;
#pragma unroll
                for (int k = 0; k < 32; k++) {
                    float4 a = w[k], x = hv[k];
                    ax += a.x * x.x; ay += a.y * x.y; az += a.z * x.z; aw2 += a.w * x.w;
                }
                gsm[c][r][bb] = (ax + ay) + (az + aw2);
            }
        }
        __syncthreads();
        if (tid < 128) {
            if (have_h) {
#pragma unroll
                for (int cc = 0; cc < 4; cc++) {
                    gi  += gsm[cc][uuc][bbc];
                    gf  += gsm[cc][16 + uuc][bbc];
                    gg2 += gsm[cc][32 + uuc][bbc];
                    go  += gsm[cc][48 + uuc][bbc];
                }
            }
            float cn = sigf(gf) * creg + sigf(gi) * tanhfast(gg2);
            float hn = sigf(go) * tanhfast(cn);
            creg = cn;
            const int b = b0 + bbc;
            outseq[((size_t)b * T + tloc) * HDIM + u0 + uuc] = hn;
            float pr = __shfl_xor(hn, 1);
            if ((uuc & 1) == 0) {
                float2 v2 = make_float2(hn, pr);
                astore64((unsigned long long*)(hwr + (size_t)b * HDIM + u0 + uuc),
                         *(unsigned long long*)&v2);
            }
        }
        postflag(&myflags[t]);
    }
}

// ---------------------------------------------------------------------------
// persistent attention. 512 blocks x 256 threads (2 blocks/CU co-resident).
// B/C role: (b = bk&63, pc = bk>>6): a1T slice [16p][512h] LDS-resident.
// A role (bk>=256): (ug = bk&31, bg = (bk>>5)&7): r.Wr / r.Wt GEMV, weights in VGPRs.
__global__ __launch_bounds__(256, 2) void att_coop(
    const float* __restrict__ a1t, const float* __restrict__ qh,
    const float* __restrict__ outp,
    const float* __restrict__ Wr, const float* __restrict__ Wt,
    const float* __restrict__ wv,
    float* __restrict__ a2r, float* __restrict__ ttgA, float* __restrict__ ttgB,
    float* __restrict__ rfull, float* __restrict__ sbuf,
    unsigned* __restrict__ flags)
{
    const int tid = threadIdx.x;
    const int bk = blockIdx.x;
    const int b = bk & 63, pc = bk >> 6;
    const int bgB = b >> 3;
    const int isA = (bk >= 256);
    const int ugA = bk & 31, bgA = (bk >> 5) & 7;
    const int u0 = ugA * 16, b0A = bgA * 8;
    unsigned* fA = flags + 1536;   // [t*8+bg], target 32
    unsigned* fB = flags + 2048;   // [t*64+b], target 8
    unsigned* fC = flags + 6144;   // [t*8+bg], target 64

    __shared__ float a1s[16][516];
    __shared__ float rst[8][528];
    __shared__ float gsm[4][32][9];
    __shared__ float a2c[512];
    __shared__ float wvs[512];
    __shared__ float scb[128];
    __shared__ float red4[4][68];

    // preload a1T slice (p-slice pc*16..+16 of batch b) — stays resident
    for (int i = tid; i < 16 * 128; i += 256) {
        int pl = i >> 7, k4 = i & 127;
        ((float4*)&a1s[pl][0])[k4] =
            ((const float4*)(a1t + (size_t)(b * PLEN + pc * 16 + pl) * HDIM))[k4];
    }
    for (int i = tid; i < 128; i += 256)
        ((float4*)wvs)[i] = ((const float4*)wv)[i];

    float4 w[32];
    const int rA = tid & 31, bh = (tid >> 5) & 1, cA = tid >> 6;
    if (isA) {
        const float* W = (rA < 16) ? Wr : Wt;
        const float4* src = (const float4*)(W + (size_t)(u0 + (rA & 15)) * HDIM) + cA * 32;
#pragma unroll
        for (int k = 0; k < 32; k++) w[k] = src[k];
    }
    __syncthreads();

    const int bbc = tid >> 4, uuc = tid & 15;

    for (int t = 0; t < HLEN; t++) {
        float* ttcur = (t & 1) ? ttgB : ttgA;
        const float* ttprev = (t & 1) ? ttgA : ttgB;

        // ---- phase A (blocks >=256, t>=1): a2r = r.Wr^T, tt = tanh(r.Wt^T)
        if (isA && t > 0) {
            waitflag(&fC[(t - 1) * 8 + bgA], 64u);
            // stage r = rfull + tt_prev, chunk-padded
            for (int i = tid; i < 8 * 512; i += 256) {
                int bb = i >> 9, u = i & 511;
                int gb = b0A + bb;
                float acc = aload32f(rfull + ((size_t)gb << 9) + u)
                          + aload32f(ttprev + ((size_t)gb << 9) + u);
                rst[bb][u + ((u >> 7) << 2)] = acc;
            }
            __syncthreads();
#pragma unroll 1
            for (int bbi = 0; bbi < 4; bbi++) {
                int bb = bh * 4 + bbi;
                const float4* hv = (const float4*)&rst[bb][cA * 132];
                float ax = 0.f, ay = 0.f, az = 0.f, aw2 = 0.f;
#pragma unroll
                for (int k = 0; k < 32; k++) {
                    float4 a = w[k], x = hv[k];
                    ax += a.x * x.x; ay += a.y * x.y; az += a.z * x.z; aw2 += a.w * x.w;
                }
                gsm[cA][rA][bb] = (ax + ay) + (az + aw2);
            }
            __syncthreads();
            if (tid < 128) {
                float a2v = 0.f, atv = 0.f;
#pragma unroll
                for (int cc = 0; cc < 4; cc++) {
                    a2v += gsm[cc][uuc][bbc];
                    atv += gsm[cc][16 + uuc][bbc];
                }
                astore32f(a2r + ((size_t)(b0A + bbc) << 9) + u0 + uuc, a2v);
                astore32f(ttcur + ((size_t)(b0A + bbc) << 9) + u0 + uuc, tanhfast(atv));
            }
            postflag(&fA[t * 8 + bgA]);
        }

        // ---- phase B: s[b][p-slice] = sum_h wv[h]*tanh(a1T + qh + a2r)
        if (t > 0) waitflag(&fA[t * 8 + bgB], 32u);
        {
            const float* qhp = qh + ((size_t)(b * HLEN + t) << 9);
            for (int i = tid; i < 512; i += 256) {
                float v = qhp[i];
                if (t > 0) v += aload32f(a2r + ((size_t)b << 9) + i);
                a2c[i] = v;
            }
        }
        __syncthreads();
        {
            const int wq = tid >> 6, l = tid & 63;
#pragma unroll
            for (int i = 0; i < 4; i++) {
                int pl = wq * 4 + i;
                const float4* arow = (const float4*)&a1s[pl][0];
                float4 a0 = arow[l], a1v = arow[l + 64];
                float4 q0 = ((float4*)a2c)[l], q1 = ((float4*)a2c)[l + 64];
                float4 v0 = ((float4*)wvs)[l], v1 = ((float4*)wvs)[l + 64];
                float s = v0.x * tanhfast(a0.x + q0.x) + v0.y * tanhfast(a0.y + q0.y)
                        + v0.z * tanhfast(a0.z + q0.z) + v0.w * tanhfast(a0.w + q0.w)
                        + v1.x * tanhfast(a1v.x + q1.x) + v1.y * tanhfast(a1v.y + q1.y)
                        + v1.z * tanhfast(a1v.z + q1.z) + v1.w * tanhfast(a1v.w + q1.w);
#pragma unroll
                for (int o = 1; o < 64; o <<= 1) s += __shfl_xor(s, o);
                if (l == 0) astore32f(sbuf + b * PLEN + pc * 16 + pl, s);
            }
        }
        postflag(&fB[t * 64 + b]);

        // ---- phase C: softmax over all p + full-r for u-slice pc*64..+64
        waitflag(&fB[t * 64 + b], 8u);
        if (tid < 128) scb[tid] = aload32f(sbuf + b * PLEN + tid);
        __syncthreads();
        if (tid < 64) {
            float v0 = scb[tid], v1 = scb[tid + 64];
            float m = fmaxf(v0, v1);
            for (int o = 32; o; o >>= 1) m = fmaxf(m, __shfl_xor(m, o));
            float e0 = __expf(v0 - m), e1 = __expf(v1 - m);
            float ss = e0 + e1;
            for (int o = 32; o; o >>= 1) ss += __shfl_xor(ss, o);
            float inv = 1.0f / ss;
            scb[tid] = e0 * inv;
            scb[tid + 64] = e1 * inv;
        }
        __syncthreads();
        {
            const int pg = tid >> 6, ul = tid & 63;
            const int ub = pc * 64;
            float acc = 0.f;
            const float* opb = outp + (((size_t)b * PLEN + pg * 32) << 9) + ub + ul;
#pragma unroll 4
            for (int j = 0; j < 32; j++)
                acc += scb[pg * 32 + j] * opb[(size_t)j << 9];
            red4[pg][ul] = acc;
        }
        __syncthreads();
        if (tid < 64) {
            float rv = red4[0][tid] + red4[1][tid] + red4[2][tid] + red4[3][tid];
            astore32f(rfull + ((size_t)b << 9) + pc * 64 + tid, rv);
        }
        postflag(&fC[t * 8 + bgB]);
    }
}

// ---------------------------------------------------------------------------
// final: rep = tanh((rfull+ttgB).fc1^T + b1 + hn.fc2^T + b2); out = rep.fc3^T + b3
__global__ __launch_bounds__(256) void final_kernel(
    const float* __restrict__ rfull, const float* __restrict__ ttb,
    const float* __restrict__ outh,
    const float* __restrict__ fc1w, const float* __restrict__ fc1b,
    const float* __restrict__ fc2w, const float* __restrict__ fc2b,
    const float* __restrict__ fc3w, const float* __restrict__ fc3b,
    float* __restrict__ out)
{
    int b = blockIdx.x, tid = threadIdx.x;
    __shared__ float rs[HDIM], hs[HDIM], rep[HDIM], red[256];
    for (int i = tid; i < HDIM; i += 256) {
        rs[i] = rfull[((size_t)b << 9) + i] + ttb[((size_t)b << 9) + i];
        hs[i] = outh[((size_t)(b * HLEN + HLEN - 1) << 9) + i];
    }
    __syncthreads();
    for (int u = tid; u < HDIM; u += 256) {
        const float4* w1 = (const float4*)(fc1w + (size_t)u * HDIM);
        const float4* w2 = (const float4*)(fc2w + (size_t)u * HDIM);
        float a = 0.f, bacc = 0.f;
        for (int k = 0; k < 128; k++) {
            float4 rv = ((float4*)rs)[k], hv = ((float4*)hs)[k];
            float4 x = w1[k]; a    += rv.x * x.x + rv.y * x.y + rv.z * x.z + rv.w * x.w;
            float4 y = w2[k]; bacc += hv.x * y.x + hv.y * y.y + hv.z * y.z + hv.w * y.w;
        }
        rep[u] = tanhfast(a + fc1b[u] + bacc + fc2b[u]);
    }
    __syncthreads();
    for (int cix = 0; cix < NCLS; cix++) {
        red[tid] = rep[tid] * fc3w[(size_t)cix * HDIM + tid]
                 + rep[tid + 256] * fc3w[(size_t)cix * HDIM + tid + 256];
        __syncthreads();
        for (int off = 128; off; off >>= 1) {
            if (tid < off) red[tid] += red[tid + off];
            __syncthreads();
        }
        if (tid == 0) out[b * NCLS + cix] = red[0] + fc3b[cix];
        __syncthreads();
    }
}

// ---------------------------------------------------------------------------
extern "C" void kernel_launch(void* const* d_in, const int* in_sizes, int n_in,
                              void* d_out, int out_size, void* d_ws, size_t ws_size,
                              hipStream_t stream)
{
    const int*   premise = (const int*)d_in[0];
    const int*   hyp     = (const int*)d_in[1];
    const float* emb     = (const float*)d_in[2];
    const float* Wih1    = (const float*)d_in[3];
    const float* Whh1    = (const float*)d_in[4];
    const float* bih1    = (const float*)d_in[5];
    const float* bhh1    = (const float*)d_in[6];
    const float* Wih2    = (const float*)d_in[7];
    const float* Whh2    = (const float*)d_in[8];
    const float* bih2    = (const float*)d_in[9];
    const float* bhh2    = (const float*)d_in[10];
    const float* Wy      = (const float*)d_in[11];
    const float* Wh      = (const float*)d_in[12];
    const float* Wr      = (const float*)d_in[13];
    const float* Wt      = (const float*)d_in[14];
    const float* wv      = (const float*)d_in[15];
    const float* fc1w    = (const float*)d_in[16];
    const float* fc1b    = (const float*)d_in[17];
    const float* fc2w    = (const float*)d_in[18];
    const float* fc2b    = (const float*)d_in[19];
    const float* fc3w    = (const float*)d_in[20];
    const float* fc3b    = (const float*)d_in[21];
    float* out = (float*)d_out;

    float* ws = (float*)d_ws;
    size_t off = 0;
    float* xp    = ws + off; off += (size_t)BSZ * PLEN * G4;
    float* xh    = ws + off; off += (size_t)BSZ * HLEN * G4;
    float* outp  = ws + off; off += (size_t)BSZ * PLEN * HDIM;
    float* outhp = ws + off; off += (size_t)BSZ * HLEN * HDIM;
    float* a1t   = ws + off; off += (size_t)BSZ * PLEN * HDIM;
    float* qhb   = ws + off; off += (size_t)BSZ * HLEN * HDIM;
    float* hAb   = ws + off; off += BSZ * HDIM;
    float* hBb   = ws + off; off += BSZ * HDIM;
    float* a2rb  = ws + off; off += BSZ * HDIM;
    float* ttgB  = ws + off; off += BSZ * HDIM;
    float* rfull = ws + off; off += BSZ * HDIM;
    float* sbuf  = ws + off; off += BSZ * PLEN;
    // zero region: flags (8192 u32) + ttgA (32768 f32), zeroed each call
    unsigned* flags = (unsigned*)(ws + off); off += 8192;
    float* ttgA = ws + off; off += BSZ * HDIM;
    if (ws_size < off * sizeof(float)) return;

    // re-zero flags + ttgA every call (graph node -> re-zeroed on each replay)
    zero_u32<<<dim3(160), dim3(256), 0, stream>>>(flags, 8192 + BSZ * HDIM);

    // input projections (biases folded in)
    proj_kernel<<<dim3(BSZ * PLEN / 16, G4 / 32), dim3(256), 0, stream>>>(
        premise, emb, Wih1, bih1, bhh1, xp);
    proj_kernel<<<dim3(BSZ * HLEN / 16, G4 / 32), dim3(256), 0, stream>>>(
        hyp, emb, Wih2, bih2, bhh2, xh);

    // both LSTMs, persistent, per-b-group flag sync
    lstm_coop<<<dim3(256), dim3(256), 0, stream>>>(
        xp, xh, Whh1, Whh2, outp, outhp, hAb, hBb, flags);

    // recurrence-free GEMMs: qh[b][t][u] = outh.Wh^T ; a1t[b][p][h] = outp.Wy^T
    gemm16<<<dim3(BSZ * HLEN / 16, HDIM / 16), dim3(256), 0, stream>>>(outhp, Wh, qhb);
    gemm16<<<dim3(BSZ * PLEN / 16, HDIM / 16), dim3(256), 0, stream>>>(outp, Wy, a1t);

    // attention recurrence, persistent (512 blocks, 2/CU)
    att_coop<<<dim3(512), dim3(256), 0, stream>>>(
        a1t, qhb, outp, Wr, Wt, wv, a2rb, ttgA, ttgB, rfull, sbuf, flags);

    // final classifier: r_63 = rfull + ttgB (t=63 odd)
    final_kernel<<<dim3(BSZ), dim3(256), 0, stream>>>(
        rfull, ttgB, outhp, fc1w, fc1b, fc2w, fc2b, fc3w, fc3b, out);
}

// Round 6
// 6457.607 us; speedup vs baseline: 1.2466x; 1.2466x over previous
//
#include <hip/hip_runtime.h>
#include <math.h>

#define BSZ 64
#define PLEN 128
#define HLEN 64
#define EDIM 300
#define HDIM 512
#define G4 2048   // 4*HDIM
#define NCLS 3

__device__ __forceinline__ float sigf(float x) { return 1.0f / (1.0f + __expf(-x)); }
__device__ __forceinline__ float tanhfast(float x) { return 1.0f - 2.0f / (__expf(2.0f * x) + 1.0f); }

// LLC-coherent relaxed agent-scope atomics (bypass non-coherent XCD L2)
__device__ __forceinline__ unsigned long long aload64(const unsigned long long* p) {
    return __hip_atomic_load(p, __ATOMIC_RELAXED, __HIP_MEMORY_SCOPE_AGENT);
}
__device__ __forceinline__ void astore64(unsigned long long* p, unsigned long long v) {
    __hip_atomic_store(p, v, __ATOMIC_RELAXED, __HIP_MEMORY_SCOPE_AGENT);
}
// tagged value: hi32 = step tag (>=1; 0 = invalid/cleared), lo32 = fp32 bits
__device__ __forceinline__ unsigned long long packtv(unsigned tag, float x) {
    return ((unsigned long long)tag << 32) | (unsigned long long)__float_as_uint(x);
}
__device__ __forceinline__ float spin64(const unsigned long long* p, unsigned tag,
                                        unsigned long long v0) {
    unsigned long long v = v0;
    while ((unsigned)(v >> 32) != tag) {
        __builtin_amdgcn_s_sleep(1);
        v = aload64(p);
    }
    return __uint_as_float((unsigned)v);
}

__global__ __launch_bounds__(256) void zero_u32(unsigned* p, int n) {
    int i = blockIdx.x * 256 + threadIdx.x;
    if (i < n) p[i] = 0u;
}

// ---------------------------------------------------------------------------
// input projection GEMM: out[m][row] = emb[toks[m]] . Wih[row] + bih[row]+bhh[row]
__global__ __launch_bounds__(256) void proj_kernel(
    const int* __restrict__ toks, const float* __restrict__ emb,
    const float* __restrict__ Wih, const float* __restrict__ bih,
    const float* __restrict__ bhh, float* __restrict__ out)
{
    __shared__ float es[16][EDIM];
    __shared__ float wsh[32][EDIM];
    int m0 = blockIdx.x * 16, r0 = blockIdx.y * 32;
    int tid = threadIdx.x;
    for (int i = tid; i < 16 * 75; i += 256) {
        int tk = i / 75, k4 = i % 75;
        ((float4*)&es[tk][0])[k4] = ((const float4*)(emb + (size_t)toks[m0 + tk] * EDIM))[k4];
    }
    for (int i = tid; i < 32 * 75; i += 256) {
        int r = i / 75, k4 = i % 75;
        ((float4*)&wsh[r][0])[k4] = ((const float4*)(Wih + (size_t)(r0 + r) * EDIM))[k4];
    }
    __syncthreads();
    int tx = tid & 31, ty = tid >> 5;
    const float4* w4 = (const float4*)&wsh[tx][0];
    const float4* e0 = (const float4*)&es[ty][0];
    const float4* e1 = (const float4*)&es[ty + 8][0];
    float a0 = 0.f, a1 = 0.f;
#pragma unroll 5
    for (int k = 0; k < 75; k++) {
        float4 w = w4[k];
        float4 x = e0[k]; a0 += x.x * w.x + x.y * w.y + x.z * w.z + x.w * w.w;
        float4 y = e1[k]; a1 += y.x * w.x + y.y * w.y + y.z * w.z + y.w * w.w;
    }
    float bsum = bih[r0 + tx] + bhh[r0 + tx];
    out[(size_t)(m0 + ty) * G4 + r0 + tx]     = a0 + bsum;
    out[(size_t)(m0 + ty + 8) * G4 + r0 + tx] = a1 + bsum;
}

// ---------------------------------------------------------------------------
// generic 16x16-tile GEMM: out[m][n] = sum_k A[m][k] * W[n][k], K = 512
__global__ __launch_bounds__(256) void gemm16(
    const float* __restrict__ A, const float* __restrict__ W,
    float* __restrict__ out)
{
    __shared__ float as[16][260];
    __shared__ float wsh2[16][260];
    int m0 = blockIdx.x * 16, n0 = blockIdx.y * 16;
    int tid = threadIdx.x, tx = tid & 15, ty = tid >> 4;
    float acc = 0.f;
    for (int kc = 0; kc < 2; kc++) {
        __syncthreads();
        for (int i = tid; i < 16 * 64; i += 256) {
            int row = i >> 6, k4 = i & 63;
            ((float4*)&as[row][0])[k4] =
                ((const float4*)(A + (size_t)(m0 + row) * HDIM + kc * 256))[k4];
            ((float4*)&wsh2[row][0])[k4] =
                ((const float4*)(W + (size_t)(n0 + row) * HDIM + kc * 256))[k4];
        }
        __syncthreads();
        const float4* av = (const float4*)&as[ty][0];
        const float4* wv4 = (const float4*)&wsh2[tx][0];
#pragma unroll 8
        for (int k = 0; k < 64; k++) {
            float4 a = av[k], ww = wv4[k];
            acc += a.x * ww.x + a.y * ww.y + a.z * ww.z + a.w * ww.w;
        }
    }
    out[(size_t)(m0 + ty) * HDIM + n0 + tx] = acc;
}

// ---------------------------------------------------------------------------
// persistent LSTM, TAGGED h exchange (no flags, no counters).
// 256 blocks = (ug 0..31: 16 units, bg 0..7: 8 batches).
// h produced at step t -> hT[t&1], tag t+1. Consumer at step t reads hT[(t-1)&1] tag t.
__global__ __launch_bounds__(256, 1) void lstm_coop(
    const float* __restrict__ xp, const float* __restrict__ xh,
    const float* __restrict__ Whh1, const float* __restrict__ Whh2,
    float* __restrict__ outp, float* __restrict__ outh,
    unsigned long long* __restrict__ hT)
{
    const int tid = threadIdx.x;
    const int ug = blockIdx.x & 31;
    const int bg = blockIdx.x >> 5;
    const int u0 = ug * 16, b0 = bg * 8;
    const int r = tid & 63;       // gate-row: g = r>>4, unit = r&15
    const int c = tid >> 6;       // k-chunk (wave index)
    const int g = r >> 4, uu = r & 15;

    __shared__ float hst[8][528];     // chunk-padded: chunk c at float offset c*132
    __shared__ float gsm[4][64][9];

    float4 w[32];
    {
        const float4* src = (const float4*)(Whh1 + (size_t)(g * HDIM + u0 + uu) * HDIM) + c * 32;
#pragma unroll
        for (int k = 0; k < 32; k++) w[k] = src[k];
    }
    float creg = 0.0f;
    const int bbc = tid >> 4, uuc = tid & 15;

    for (int t = 0; t < PLEN + HLEN; t++) {
        const int layer2 = (t >= PLEN) ? 1 : 0;
        const int tloc = layer2 ? t - PLEN : t;
        const int T = layer2 ? HLEN : PLEN;
        const float* xproj = layer2 ? xh : xp;
        float* outseq = layer2 ? outh : outp;

        if (t == PLEN) {
            const float4* src = (const float4*)(Whh2 + (size_t)(g * HDIM + u0 + uu) * HDIM) + c * 32;
#pragma unroll
            for (int k = 0; k < 32; k++) w[k] = src[k];
        }
        // prefetch xproj gates (plain loads, independent of h)
        float gi = 0.f, gf = 0.f, gg2 = 0.f, go = 0.f;
        if (tid < 128) {
            size_t xb = ((size_t)(b0 + bbc) * T + tloc) * G4 + u0 + uuc;
            gi = xproj[xb]; gf = xproj[xb + 512];
            gg2 = xproj[xb + 1024]; go = xproj[xb + 1536];
        }
        const bool have_h = (tloc != 0);
        if (have_h) {
            const unsigned long long* src =
                hT + ((size_t)((t - 1) & 1) << 15) + ((size_t)b0 << 9);
            const unsigned tg = (unsigned)t;
            unsigned long long v[16];
#pragma unroll
            for (int i = 0; i < 16; i++) v[i] = aload64(src + tid + i * 256);
#pragma unroll
            for (int i = 0; i < 16; i++) {
                float hv = spin64(src + tid + i * 256, tg, v[i]);
                int idx = tid + i * 256;
                int bb = idx >> 9, u = idx & 511;
                hst[bb][u + ((u >> 7) << 2)] = hv;
            }
            __syncthreads();
            // GEMV: all 64 lanes of a wave read the SAME hst address (broadcast)
#pragma unroll 1
            for (int bb = 0; bb < 8; bb++) {
                const float4* hv = (const float4*)&hst[bb][c * 132];
                float ax = 0.f, ay = 0.f, az = 0.f, aw2 = 0.f;
#pragma unroll
                for (int k = 0; k < 32; k++) {
                    float4 a = w[k], x = hv[k];
                    ax += a.x * x.x; ay += a.y * x.y; az += a.z * x.z; aw2 += a.w * x.w;
                }
                gsm[c][r][bb] = (ax + ay) + (az + aw2);
            }
        }
        __syncthreads();
        if (tid < 128) {
            if (have_h) {
#pragma unroll
                for (int cc = 0; cc < 4; cc++) {
                    gi  += gsm[cc][uuc][bbc];
                    gf  += gsm[cc][16 + uuc][bbc];
                    gg2 += gsm[cc][32 + uuc][bbc];
                    go  += gsm[cc][48 + uuc][bbc];
                }
            }
            float cn = sigf(gf) * creg + sigf(gi) * tanhfast(gg2);
            float hn = sigf(go) * tanhfast(cn);
            creg = cn;
            const int b = b0 + bbc;
            outseq[((size_t)b * T + tloc) * HDIM + u0 + uuc] = hn;
            astore64(hT + ((size_t)(t & 1) << 15) + ((size_t)b << 9) + u0 + uuc,
                     packtv((unsigned)(t + 1), hn));
        }
        // no flag, no waitcnt: tag rides with the data
    }
}

// ---------------------------------------------------------------------------
// persistent attention, TAGGED exchange. 512 blocks x 256 threads (2/CU).
// All blocks: B/C role for (b = bk&63, pc = bk>>6): p-slice pc*16.., u-slice pc*64..
// Blocks bk<256 additionally: A role (ugA 16 units, bgA 8 batches), Wr/Wt in VGPRs.
// Products of step t carry tag t+1. Chain per b: A(t)->B(t)->C(t)->A(t+1) strictly
// serial => single-copy tagged buffers are race-free.
__global__ __launch_bounds__(256, 2) void att_coop(
    const float* __restrict__ a1t, const float* __restrict__ qh,
    const float* __restrict__ outp,
    const float* __restrict__ Wr, const float* __restrict__ Wt,
    const float* __restrict__ wv,
    unsigned long long* __restrict__ a2rT, unsigned long long* __restrict__ ttaT,
    unsigned long long* __restrict__ sbufT, unsigned long long* __restrict__ rfullT)
{
    const int tid = threadIdx.x;
    const int bk = blockIdx.x;
    const int b = bk & 63, pc = bk >> 6;
    const int isA = (bk < 256);
    const int ugA = bk & 31, bgA = bk >> 5;
    const int u0 = ugA * 16, b0A = bgA * 8;

    __shared__ float a1s[16][516];
    __shared__ float rst[8][528];
    __shared__ float gsm[4][32][9];
    __shared__ float a2c[512];
    __shared__ float wvs[512];
    __shared__ float scb[128];
    __shared__ float red4[4][68];

    // preload a1T slice (16 p of batch b) — resident for the whole kernel
    for (int i = tid; i < 16 * 128; i += 256) {
        int pl = i >> 7, k4 = i & 127;
        ((float4*)&a1s[pl][0])[k4] =
            ((const float4*)(a1t + (size_t)(b * PLEN + pc * 16 + pl) * HDIM))[k4];
    }
    for (int i = tid; i < 128; i += 256)
        ((float4*)wvs)[i] = ((const float4*)wv)[i];

    float4 w[32];
    const int rA = tid & 31, bh = (tid >> 5) & 1, cA = tid >> 6;
    if (isA) {
        const float* W = (rA < 16) ? Wr : Wt;
        const float4* src = (const float4*)(W + (size_t)(u0 + (rA & 15)) * HDIM) + cA * 32;
#pragma unroll
        for (int k = 0; k < 32; k++) w[k] = src[k];
    }
    __syncthreads();

    const int bbc = tid >> 4, uuc = tid & 15;

    for (int t = 0; t < HLEN; t++) {
        const unsigned tagw = (unsigned)(t + 1);   // tag of products of step t

        // ---- phase A (blocks <256, t>=1): a2 = r.Wr^T, tt = tanh(r.Wt^T)
        if (isA && t > 0) {
            const unsigned long long* src = rfullT + ((size_t)b0A << 9);
            const unsigned tg = (unsigned)t;       // product of step t-1
            unsigned long long v[16];
#pragma unroll
            for (int i = 0; i < 16; i++) v[i] = aload64(src + tid + i * 256);
#pragma unroll
            for (int i = 0; i < 16; i++) {
                float rv = spin64(src + tid + i * 256, tg, v[i]);
                int idx = tid + i * 256;
                int bb = idx >> 9, u = idx & 511;
                rst[bb][u + ((u >> 7) << 2)] = rv;
            }
            __syncthreads();
#pragma unroll 1
            for (int bbi = 0; bbi < 4; bbi++) {
                int bb = bh * 4 + bbi;
                const float4* hv = (const float4*)&rst[bb][cA * 132];
                float ax = 0.f, ay = 0.f, az = 0.f, aw2 = 0.f;
#pragma unroll
                for (int k = 0; k < 32; k++) {
                    float4 a = w[k], x = hv[k];
                    ax += a.x * x.x; ay += a.y * x.y; az += a.z * x.z; aw2 += a.w * x.w;
                }
                gsm[cA][rA][bb] = (ax + ay) + (az + aw2);
            }
            __syncthreads();
            if (tid < 128) {
                float a2v = 0.f, atv = 0.f;
#pragma unroll
                for (int cc = 0; cc < 4; cc++) {
                    a2v += gsm[cc][uuc][bbc];
                    atv += gsm[cc][16 + uuc][bbc];
                }
                size_t o = ((size_t)(b0A + bbc) << 9) + u0 + uuc;
                astore64(a2rT + o, packtv(tagw, a2v));
                astore64(ttaT + o, packtv(tagw, tanhfast(atv)));
            }
        }

        // ---- phase B: stage a2c = qh[b][t] (+ tagged a2r), compute 16 scores
        {
            const float* qp = qh + ((size_t)(b * HLEN + t) << 9);
#pragma unroll
            for (int i = 0; i < 2; i++) {
                int idx = tid + i * 256;
                float v = qp[idx];
                if (t > 0) {
                    const unsigned long long* p = a2rT + ((size_t)b << 9) + idx;
                    v += spin64(p, tagw, aload64(p));
                }
                a2c[idx] = v;
            }
        }
        __syncthreads();
        {
            const int wq = tid >> 6, l = tid & 63;
#pragma unroll
            for (int i = 0; i < 4; i++) {
                int pl = wq * 4 + i;
                const float4* arow = (const float4*)&a1s[pl][0];
                float4 a0 = arow[l], a1v = arow[l + 64];
                float4 q0 = ((float4*)a2c)[l], q1 = ((float4*)a2c)[l + 64];
                float4 v0 = ((float4*)wvs)[l], v1 = ((float4*)wvs)[l + 64];
                float s = v0.x * tanhfast(a0.x + q0.x) + v0.y * tanhfast(a0.y + q0.y)
                        + v0.z * tanhfast(a0.z + q0.z) + v0.w * tanhfast(a0.w + q0.w)
                        + v1.x * tanhfast(a1v.x + q1.x) + v1.y * tanhfast(a1v.y + q1.y)
                        + v1.z * tanhfast(a1v.z + q1.z) + v1.w * tanhfast(a1v.w + q1.w);
#pragma unroll
                for (int o = 1; o < 64; o <<= 1) s += __shfl_xor(s, o);
                if (l == 0)
                    astore64(sbufT + b * PLEN + pc * 16 + pl, packtv(tagw, s));
            }
        }

        // ---- phase C: softmax over all p + r-slice (64 u) update
        if (tid < 128) {
            const unsigned long long* p = sbufT + b * PLEN + tid;
            scb[tid] = spin64(p, tagw, aload64(p));
        }
        __syncthreads();
        if (tid < 64) {
            float v0 = scb[tid], v1 = scb[tid + 64];
            float m = fmaxf(v0, v1);
            for (int o = 32; o; o >>= 1) m = fmaxf(m, __shfl_xor(m, o));
            float e0 = __expf(v0 - m), e1 = __expf(v1 - m);
            float ss = e0 + e1;
            for (int o = 32; o; o >>= 1) ss += __shfl_xor(ss, o);
            float inv = 1.0f / ss;
            scb[tid] = e0 * inv;
            scb[tid + 64] = e1 * inv;
        }
        __syncthreads();
        {
            const int pg = tid >> 6, ul = tid & 63;
            float acc = 0.f;
            const float* opb = outp + (((size_t)b * PLEN + pg * 32) << 9) + pc * 64 + ul;
#pragma unroll 4
            for (int j = 0; j < 32; j++)
                acc += scb[pg * 32 + j] * opb[(size_t)j << 9];
            red4[pg][ul] = acc;
        }
        __syncthreads();
        if (tid < 64) {
            float rv = red4[0][tid] + red4[1][tid] + red4[2][tid] + red4[3][tid];
            if (t > 0) {
                const unsigned long long* p = ttaT + ((size_t)b << 9) + pc * 64 + tid;
                rv += spin64(p, tagw, aload64(p));
            }
            astore64(rfullT + ((size_t)b << 9) + pc * 64 + tid, packtv(tagw, rv));
        }
    }
}

// ---------------------------------------------------------------------------
// final: rep = tanh(r.fc1^T + b1 + hn.fc2^T + b2); out = rep.fc3^T + b3
// r comes from rfullT (tagged u64, strip tag).
__global__ __launch_bounds__(256) void final_kernel(
    const unsigned long long* __restrict__ rfullT, const float* __restrict__ outh,
    const float* __restrict__ fc1w, const float* __restrict__ fc1b,
    const float* __restrict__ fc2w, const float* __restrict__ fc2b,
    const float* __restrict__ fc3w, const float* __restrict__ fc3b,
    float* __restrict__ out)
{
    int b = blockIdx.x, tid = threadIdx.x;
    __shared__ float rs[HDIM], hs[HDIM], rep[HDIM], red[256];
    for (int i = tid; i < HDIM; i += 256) {
        rs[i] = __uint_as_float((unsigned)rfullT[((size_t)b << 9) + i]);
        hs[i] = outh[((size_t)(b * HLEN + HLEN - 1) << 9) + i];
    }
    __syncthreads();
    for (int u = tid; u < HDIM; u += 256) {
        const float4* w1 = (const float4*)(fc1w + (size_t)u * HDIM);
        const float4* w2 = (const float4*)(fc2w + (size_t)u * HDIM);
        float a = 0.f, bacc = 0.f;
        for (int k = 0; k < 128; k++) {
            float4 rv = ((float4*)rs)[k], hv = ((float4*)hs)[k];
            float4 x = w1[k]; a    += rv.x * x.x + rv.y * x.y + rv.z * x.z + rv.w * x.w;
            float4 y = w2[k]; bacc += hv.x * y.x + hv.y * y.y + hv.z * y.z + hv.w * y.w;
        }
        rep[u] = tanhfast(a + fc1b[u] + bacc + fc2b[u]);
    }
    __syncthreads();
    for (int cix = 0; cix < NCLS; cix++) {
        red[tid] = rep[tid] * fc3w[(size_t)cix * HDIM + tid]
                 + rep[tid + 256] * fc3w[(size_t)cix * HDIM + tid + 256];
        __syncthreads();
        for (int off = 128; off; off >>= 1) {
            if (tid < off) red[tid] += red[tid + off];
            __syncthreads();
        }
        if (tid == 0) out[b * NCLS + cix] = red[0] + fc3b[cix];
        __syncthreads();
    }
}

// ---------------------------------------------------------------------------
extern "C" void kernel_launch(void* const* d_in, const int* in_sizes, int n_in,
                              void* d_out, int out_size, void* d_ws, size_t ws_size,
                              hipStream_t stream)
{
    const int*   premise = (const int*)d_in[0];
    const int*   hyp     = (const int*)d_in[1];
    const float* emb     = (const float*)d_in[2];
    const float* Wih1    = (const float*)d_in[3];
    const float* Whh1    = (const float*)d_in[4];
    const float* bih1    = (const float*)d_in[5];
    const float* bhh1    = (const float*)d_in[6];
    const float* Wih2    = (const float*)d_in[7];
    const float* Whh2    = (const float*)d_in[8];
    const float* bih2    = (const float*)d_in[9];
    const float* bhh2    = (const float*)d_in[10];
    const float* Wy      = (const float*)d_in[11];
    const float* Wh      = (const float*)d_in[12];
    const float* Wr      = (const float*)d_in[13];
    const float* Wt      = (const float*)d_in[14];
    const float* wv      = (const float*)d_in[15];
    const float* fc1w    = (const float*)d_in[16];
    const float* fc1b    = (const float*)d_in[17];
    const float* fc2w    = (const float*)d_in[18];
    const float* fc2b    = (const float*)d_in[19];
    const float* fc3w    = (const float*)d_in[20];
    const float* fc3b    = (const float*)d_in[21];
    float* out = (float*)d_out;

    float* ws = (float*)d_ws;
    size_t off = 0;
    float* xp    = ws + off; off += (size_t)BSZ * PLEN * G4;
    float* xh    = ws + off; off += (size_t)BSZ * HLEN * G4;
    float* outp  = ws + off; off += (size_t)BSZ * PLEN * HDIM;
    float* outhp = ws + off; off += (size_t)BSZ * HLEN * HDIM;
    float* a1t   = ws + off; off += (size_t)BSZ * PLEN * HDIM;
    float* qhb   = ws + off; off += (size_t)BSZ * HLEN * HDIM;
    // tagged u64 buffers (contiguous; tags zeroed each call)
    unsigned* tagbase = (unsigned*)(ws + off);
    unsigned long long* hT     = (unsigned long long*)(ws + off); off += 2 * BSZ * HDIM * 2;
    unsigned long long* a2rT   = (unsigned long long*)(ws + off); off += BSZ * HDIM * 2;
    unsigned long long* ttaT   = (unsigned long long*)(ws + off); off += BSZ * HDIM * 2;
    unsigned long long* sbufT  = (unsigned long long*)(ws + off); off += BSZ * PLEN * 2;
    unsigned long long* rfullT = (unsigned long long*)(ws + off); off += BSZ * HDIM * 2;
    if (ws_size < off * sizeof(float)) return;

    // clear all tags every call (graph node -> re-cleared on every replay)
    {
        int n = 2 * BSZ * HDIM * 2 + 3 * BSZ * HDIM * 2 + BSZ * PLEN * 2;
        zero_u32<<<dim3((n + 255) / 256), dim3(256), 0, stream>>>(tagbase, n);
    }

    // input projections (biases folded in)
    proj_kernel<<<dim3(BSZ * PLEN / 16, G4 / 32), dim3(256), 0, stream>>>(
        premise, emb, Wih1, bih1, bhh1, xp);
    proj_kernel<<<dim3(BSZ * HLEN / 16, G4 / 32), dim3(256), 0, stream>>>(
        hyp, emb, Wih2, bih2, bhh2, xh);

    // both LSTMs, persistent, tagged h exchange
    lstm_coop<<<dim3(256), dim3(256), 0, stream>>>(
        xp, xh, Whh1, Whh2, outp, outhp, hT);

    // recurrence-free GEMMs: qh[b][t][u] = outh.Wh^T ; a1t[b][p][h] = outp.Wy^T
    gemm16<<<dim3(BSZ * HLEN / 16, HDIM / 16), dim3(256), 0, stream>>>(outhp, Wh, qhb);
    gemm16<<<dim3(BSZ * PLEN / 16, HDIM / 16), dim3(256), 0, stream>>>(outp, Wy, a1t);

    // attention recurrence, persistent, tagged 3-hop pipeline
    att_coop<<<dim3(512), dim3(256), 0, stream>>>(
        a1t, qhb, outp, Wr, Wt, wv, a2rT, ttaT, sbufT, rfullT);

    // final classifier (r = rfullT payloads, tag 64)
    final_kernel<<<dim3(BSZ), dim3(256), 0, stream>>>(
        rfullT, outhp, fc1w, fc1b, fc2w, fc2b, fc3w, fc3b, out);
}

// Round 7
// 6401.393 us; speedup vs baseline: 1.2576x; 1.0088x over previous
//
#include <hip/hip_runtime.h>
#include <math.h>

#define BSZ 64
#define PLEN 128
#define HLEN 64
#define EDIM 300
#define HDIM 512
#define G4 2048   // 4*HDIM
#define NCLS 3
#define LT 192    // total LSTM steps

__device__ __forceinline__ float sigf(float x) { return 1.0f / (1.0f + __expf(-x)); }
__device__ __forceinline__ float tanhfast(float x) { return 1.0f - 2.0f / (__expf(2.0f * x) + 1.0f); }

// LLC-coherent relaxed agent-scope atomics (bypass non-coherent XCD L2)
__device__ __forceinline__ float aload32f(const float* p) {
    return __hip_atomic_load(p, __ATOMIC_RELAXED, __HIP_MEMORY_SCOPE_AGENT);
}
__device__ __forceinline__ void astore32f(float* p, float v) {
    __hip_atomic_store(p, v, __ATOMIC_RELAXED, __HIP_MEMORY_SCOPE_AGENT);
}
__device__ __forceinline__ unsigned aload32u(const unsigned* p) {
    return __hip_atomic_load(p, __ATOMIC_RELAXED, __HIP_MEMORY_SCOPE_AGENT);
}
__device__ __forceinline__ void astore32u(unsigned* p, unsigned v) {
    __hip_atomic_store(p, v, __ATOMIC_RELAXED, __HIP_MEMORY_SCOPE_AGENT);
}

__global__ __launch_bounds__(256) void zero_u32(unsigned* p, int n) {
    int i = blockIdx.x * 256 + threadIdx.x;
    if (i < n) p[i] = 0u;
}

// ---------------------------------------------------------------------------
// input projection GEMM: out[m][row] = emb[toks[m]] . Wih[row] + bih[row]+bhh[row]
__global__ __launch_bounds__(256) void proj_kernel(
    const int* __restrict__ toks, const float* __restrict__ emb,
    const float* __restrict__ Wih, const float* __restrict__ bih,
    const float* __restrict__ bhh, float* __restrict__ out)
{
    __shared__ float es[16][EDIM];
    __shared__ float wsh[32][EDIM];
    int m0 = blockIdx.x * 16, r0 = blockIdx.y * 32;
    int tid = threadIdx.x;
    for (int i = tid; i < 16 * 75; i += 256) {
        int tk = i / 75, k4 = i % 75;
        ((float4*)&es[tk][0])[k4] = ((const float4*)(emb + (size_t)toks[m0 + tk] * EDIM))[k4];
    }
    for (int i = tid; i < 32 * 75; i += 256) {
        int r = i / 75, k4 = i % 75;
        ((float4*)&wsh[r][0])[k4] = ((const float4*)(Wih + (size_t)(r0 + r) * EDIM))[k4];
    }
    __syncthreads();
    int tx = tid & 31, ty = tid >> 5;
    const float4* w4 = (const float4*)&wsh[tx][0];
    const float4* e0 = (const float4*)&es[ty][0];
    const float4* e1 = (const float4*)&es[ty + 8][0];
    float a0 = 0.f, a1 = 0.f;
#pragma unroll 5
    for (int k = 0; k < 75; k++) {
        float4 w = w4[k];
        float4 x = e0[k]; a0 += x.x * w.x + x.y * w.y + x.z * w.z + x.w * w.w;
        float4 y = e1[k]; a1 += y.x * w.x + y.y * w.y + y.z * w.z + y.w * w.w;
    }
    float bsum = bih[r0 + tx] + bhh[r0 + tx];
    out[(size_t)(m0 + ty) * G4 + r0 + tx]     = a0 + bsum;
    out[(size_t)(m0 + ty + 8) * G4 + r0 + tx] = a1 + bsum;
}

// ---------------------------------------------------------------------------
// generic 16x16-tile GEMM: out[m][n] = sum_k A[m][k] * W[n][k], K = 512
__global__ __launch_bounds__(256) void gemm16(
    const float* __restrict__ A, const float* __restrict__ W,
    float* __restrict__ out)
{
    __shared__ float as[16][260];
    __shared__ float wsh2[16][260];
    int m0 = blockIdx.x * 16, n0 = blockIdx.y * 16;
    int tid = threadIdx.x, tx = tid & 15, ty = tid >> 4;
    float acc = 0.f;
    for (int kc = 0; kc < 2; kc++) {
        __syncthreads();
        for (int i = tid; i < 16 * 64; i += 256) {
            int row = i >> 6, k4 = i & 63;
            ((float4*)&as[row][0])[k4] =
                ((const float4*)(A + (size_t)(m0 + row) * HDIM + kc * 256))[k4];
            ((float4*)&wsh2[row][0])[k4] =
                ((const float4*)(W + (size_t)(n0 + row) * HDIM + kc * 256))[k4];
        }
        __syncthreads();
        const float4* av = (const float4*)&as[ty][0];
        const float4* wv4 = (const float4*)&wsh2[tx][0];
#pragma unroll 8
        for (int k = 0; k < 64; k++) {
            float4 a = av[k], ww = wv4[k];
            acc += a.x * ww.x + a.y * ww.y + a.z * ww.z + a.w * ww.w;
        }
    }
    out[(size_t)(m0 + ty) * HDIM + n0 + tx] = acc;
}

// ---------------------------------------------------------------------------
// fused transpose: WrtT[k][row] where row<512 -> Wr[row][k], row>=512 -> Wt[row-512][k]
__global__ __launch_bounds__(256) void wtrans(
    const float* __restrict__ Wr, const float* __restrict__ Wt,
    float* __restrict__ WrtT)
{
    __shared__ float tile[32][33];
    int r0 = blockIdx.x * 32, k0 = blockIdx.y * 32;
    int tid = threadIdx.x;
    for (int i = tid; i < 1024; i += 256) {
        int rr = i >> 5, kk = i & 31;
        int row = r0 + rr;
        const float* src = (row < 512) ? (Wr + (size_t)row * HDIM)
                                       : (Wt + (size_t)(row - 512) * HDIM);
        tile[rr][kk] = src[k0 + kk];
    }
    __syncthreads();
    for (int i = tid; i < 1024; i += 256) {
        int kk = i >> 5, rr = i & 31;
        WrtT[(size_t)(k0 + kk) * 1024 + r0 + rr] = tile[rr][kk];
    }
}

// ---------------------------------------------------------------------------
// persistent LSTM, single-writer FLAG sync + issue-once bulk loads.
// 256 blocks = (ug 0..31: 16 units, bg 0..7: 8 batches). Weights in VGPRs.
// h_t written to buffer[t&1]; flag[t][bg][ug] set after drain; consumer at t
// spins on the 32 flags of (t-1, bg), then bulk-loads h once.
__global__ __launch_bounds__(256, 1) void lstm_coop(
    const float* __restrict__ xp, const float* __restrict__ xh,
    const float* __restrict__ Whh1, const float* __restrict__ Whh2,
    float* __restrict__ outp, float* __restrict__ outh,
    float* __restrict__ hA, float* __restrict__ hB,
    unsigned* __restrict__ flagsH)
{
    const int tid = threadIdx.x;
    const int ug = blockIdx.x & 31;
    const int bg = blockIdx.x >> 5;
    const int u0 = ug * 16, b0 = bg * 8;
    const int r = tid & 63;       // gate-row: g = r>>4, unit = r&15
    const int c = tid >> 6;       // k-chunk (wave index)
    const int g = r >> 4, uu = r & 15;

    __shared__ float hst[8][528];     // chunk-padded: chunk c at float offset c*132
    __shared__ float gsm[4][64][9];

    float4 w[32];
    {
        const float4* src = (const float4*)(Whh1 + (size_t)(g * HDIM + u0 + uu) * HDIM) + c * 32;
#pragma unroll
        for (int k = 0; k < 32; k++) w[k] = src[k];
    }
    float creg = 0.0f;
    const int bbc = tid >> 4, uuc = tid & 15;

    for (int t = 0; t < LT; t++) {
        const int layer2 = (t >= PLEN) ? 1 : 0;
        const int tloc = layer2 ? t - PLEN : t;
        const int T = layer2 ? HLEN : PLEN;
        const float* xproj = layer2 ? xh : xp;
        float* outseq = layer2 ? outh : outp;
        float* hwr = (t & 1) ? hB : hA;
        const float* hrd = (t & 1) ? hA : hB;   // h_{t-1} lives in buffer[(t-1)&1]

        if (t == PLEN) {
            const float4* src = (const float4*)(Whh2 + (size_t)(g * HDIM + u0 + uu) * HDIM) + c * 32;
#pragma unroll
            for (int k = 0; k < 32; k++) w[k] = src[k];
        }
        // prefetch xproj gates (plain loads, independent of h)
        float gi = 0.f, gf = 0.f, gg2 = 0.f, go = 0.f;
        if (tid < 128) {
            size_t xb = ((size_t)(b0 + bbc) * T + tloc) * G4 + u0 + uuc;
            gi = xproj[xb]; gf = xproj[xb + 512];
            gg2 = xproj[xb + 1024]; go = xproj[xb + 1536];
        }
        const bool have_h = (tloc != 0);
        if (have_h) {
            // wait: all 32 u-group producers of this bg flagged step t-1
            const unsigned* fl = flagsH + (size_t)(t - 1) * 256 + bg * 32;
            if (tid < 32) {
                while (aload32u(fl + tid) == 0u) __builtin_amdgcn_s_sleep(2);
            }
            __syncthreads();
            __asm__ volatile("" ::: "memory");
            // bulk issue-once coalesced LLC loads of h (8 b x 512)
#pragma unroll
            for (int i = 0; i < 16; i++) {
                int idx = tid + i * 256;
                float hv = aload32f(hrd + ((size_t)b0 << 9) + idx);
                int bb = idx >> 9, u = idx & 511;
                hst[bb][u + ((u >> 7) << 2)] = hv;
            }
            __syncthreads();
            // GEMV: all 64 lanes of a wave read the SAME hst address (broadcast)
#pragma unroll 1
            for (int bb = 0; bb < 8; bb++) {
                const float4* hv = (const float4*)&hst[bb][c * 132];
                float ax = 0.f, ay = 0.f, az = 0.f, aw2 = 0.f;
#pragma unroll
                for (int k = 0; k < 32; k++) {
                    float4 a = w[k], x = hv[k];
                    ax += a.x * x.x; ay += a.y * x.y; az += a.z * x.z; aw2 += a.w * x.w;
                }
                gsm[c][r][bb] = (ax + ay) + (az + aw2);
            }
        }
        __syncthreads();
        if (tid < 128) {
            if (have_h) {
#pragma unroll
                for (int cc = 0; cc < 4; cc++) {
                    gi  += gsm[cc][uuc][bbc];
                    gf  += gsm[cc][16 + uuc][bbc];
                    gg2 += gsm[cc][32 + uuc][bbc];
                    go  += gsm[cc][48 + uuc][bbc];
                }
            }
            float cn = sigf(gf) * creg + sigf(gi) * tanhfast(gg2);
            float hn = sigf(go) * tanhfast(cn);
            creg = cn;
            const int b = b0 + bbc;
            outseq[((size_t)b * T + tloc) * HDIM + u0 + uuc] = hn;
            astore32f(hwr + ((size_t)b << 9) + u0 + uuc, hn);
        }
        // single-writer flag after per-wave drain + block barrier
        __asm__ volatile("" ::: "memory");
        __builtin_amdgcn_s_waitcnt(0);
        __syncthreads();
        if (tid == 0)
            astore32u(flagsH + (size_t)t * 256 + bg * 32 + ug, 1u);
    }
}

// ---------------------------------------------------------------------------
// SYNC-FREE attention: one block per batch, 1024 threads, 64 steps in-block.
// Wr||Wt pre-transposed (WrtT[k][1024]) streamed from L2 each step; r/tt/scores
// live in LDS. No atomics, no flags, no inter-block communication.
__global__ __launch_bounds__(1024, 1) void att_local(
    const float* __restrict__ a1t,   // [b][p][h] = outp . Wy^T
    const float* __restrict__ qh,    // [b][t][u] = outh . Wh^T
    const float* __restrict__ outp,  // [b][p][u]
    const float* __restrict__ WrtT,  // [k][row] row<512: Wr, else Wt
    const float* __restrict__ wv,
    float* __restrict__ rfin)        // [b][512] final r
{
    const int b = blockIdx.x;
    const int tid = threadIdx.x;
    __shared__ float rs[512], a2s[512], tts[512], wvs[512];
    __shared__ float psum[2][1024];
    __shared__ float scb[128];
    __shared__ float rupd[2][512];

    for (int i = tid; i < 512; i += 1024) wvs[i] = wv[i];
    __syncthreads();

    for (int t = 0; t < HLEN; t++) {
        // ---- fused GEMV: [a2|tt](row) = sum_k r[k] * WrtT[k][row]
        if (t > 0) {
            const int rp = tid & 511, kh = tid >> 9;
            const float* wb = WrtT + ((size_t)kh * 256) * 1024 + rp * 2;
            const float* rk = rs + kh * 256;
            float a0 = 0.f, a1v = 0.f;
#pragma unroll 2
            for (int k = 0; k < 256; k += 4) {
                float4 r4 = *(const float4*)(rk + k);
                float2 w0 = *(const float2*)(wb + (size_t)(k + 0) * 1024);
                float2 w1 = *(const float2*)(wb + (size_t)(k + 1) * 1024);
                float2 w2 = *(const float2*)(wb + (size_t)(k + 2) * 1024);
                float2 w3 = *(const float2*)(wb + (size_t)(k + 3) * 1024);
                a0  += w0.x * r4.x + w1.x * r4.y + w2.x * r4.z + w3.x * r4.w;
                a1v += w0.y * r4.x + w1.y * r4.y + w2.y * r4.z + w3.y * r4.w;
            }
            psum[kh][rp * 2]     = a0;
            psum[kh][rp * 2 + 1] = a1v;
        }
        __syncthreads();
        {
            const int row = tid;
            float val = (t > 0) ? (psum[0][row] + psum[1][row]) : 0.f;
            if (row < 512)
                a2s[row] = qh[((size_t)(b * HLEN + t)) * HDIM + row] + val;
            else
                tts[row - 512] = (t > 0) ? tanhfast(val) : 0.f;
        }
        __syncthreads();
        // ---- scores: s[p] = sum_h wv[h] * tanh(a1t[p][h] + a2[h])
        {
            const int p = tid >> 3, hq = (tid & 7) * 16;   // 16 float4 = 64 h
            const float4* ap = (const float4*)(a1t + ((size_t)(b * PLEN + p)) * HDIM) + hq;
            const float4* aq = ((const float4*)a2s) + hq;
            const float4* wq = ((const float4*)wvs) + hq;
            float s = 0.f;
#pragma unroll 4
            for (int j = 0; j < 16; j++) {
                float4 a = ap[j], q = aq[j], ww = wq[j];
                s += ww.x * tanhfast(a.x + q.x) + ww.y * tanhfast(a.y + q.y)
                   + ww.z * tanhfast(a.z + q.z) + ww.w * tanhfast(a.w + q.w);
            }
            s += __shfl_xor(s, 1);
            s += __shfl_xor(s, 2);
            s += __shfl_xor(s, 4);
            if ((tid & 7) == 0) scb[p] = s;
        }
        __syncthreads();
        // ---- softmax over 128 p (first wave)
        if (tid < 64) {
            float v0 = scb[tid], v1 = scb[tid + 64];
            float m = fmaxf(v0, v1);
            for (int o = 32; o; o >>= 1) m = fmaxf(m, __shfl_xor(m, o));
            float e0 = __expf(v0 - m), e1 = __expf(v1 - m);
            float ss = e0 + e1;
            for (int o = 32; o; o >>= 1) ss += __shfl_xor(ss, o);
            float inv = 1.0f / ss;
            scb[tid] = e0 * inv;
            scb[tid + 64] = e1 * inv;
        }
        __syncthreads();
        // ---- r update: r[u] = sum_p scb[p] * outp[b][p][u] + tts[u]
        {
            const int u = tid & 511, ph = tid >> 9;
            const float* opb = outp + ((size_t)(b * PLEN + ph * 64)) * HDIM + u;
            float acc = 0.f;
#pragma unroll 4
            for (int j = 0; j < 64; j++)
                acc += scb[ph * 64 + j] * opb[(size_t)j * HDIM];
            rupd[ph][u] = acc;
        }
        __syncthreads();
        if (tid < 512) {
            float rv = rupd[0][tid] + rupd[1][tid] + tts[tid];
            rs[tid] = rv;
            if (t == HLEN - 1) rfin[(size_t)b * HDIM + tid] = rv;
        }
        __syncthreads();
    }
}

// ---------------------------------------------------------------------------
// final: rep = tanh(r.fc1^T + b1 + hn.fc2^T + b2); out = rep.fc3^T + b3
__global__ __launch_bounds__(256) void final_kernel(
    const float* __restrict__ rfin, const float* __restrict__ outh,
    const float* __restrict__ fc1w, const float* __restrict__ fc1b,
    const float* __restrict__ fc2w, const float* __restrict__ fc2b,
    const float* __restrict__ fc3w, const float* __restrict__ fc3b,
    float* __restrict__ out)
{
    int b = blockIdx.x, tid = threadIdx.x;
    __shared__ float rs[HDIM], hs[HDIM], rep[HDIM], red[256];
    for (int i = tid; i < HDIM; i += 256) {
        rs[i] = rfin[((size_t)b << 9) + i];
        hs[i] = outh[((size_t)(b * HLEN + HLEN - 1) << 9) + i];
    }
    __syncthreads();
    for (int u = tid; u < HDIM; u += 256) {
        const float4* w1 = (const float4*)(fc1w + (size_t)u * HDIM);
        const float4* w2 = (const float4*)(fc2w + (size_t)u * HDIM);
        float a = 0.f, bacc = 0.f;
        for (int k = 0; k < 128; k++) {
            float4 rv = ((float4*)rs)[k], hv = ((float4*)hs)[k];
            float4 x = w1[k]; a    += rv.x * x.x + rv.y * x.y + rv.z * x.z + rv.w * x.w;
            float4 y = w2[k]; bacc += hv.x * y.x + hv.y * y.y + hv.z * y.z + hv.w * y.w;
        }
        rep[u] = tanhfast(a + fc1b[u] + bacc + fc2b[u]);
    }
    __syncthreads();
    for (int cix = 0; cix < NCLS; cix++) {
        red[tid] = rep[tid] * fc3w[(size_t)cix * HDIM + tid]
                 + rep[tid + 256] * fc3w[(size_t)cix * HDIM + tid + 256];
        __syncthreads();
        for (int off = 128; off; off >>= 1) {
            if (tid < off) red[tid] += red[tid + off];
            __syncthreads();
        }
        if (tid == 0) out[b * NCLS + cix] = red[0] + fc3b[cix];
        __syncthreads();
    }
}

// ---------------------------------------------------------------------------
extern "C" void kernel_launch(void* const* d_in, const int* in_sizes, int n_in,
                              void* d_out, int out_size, void* d_ws, size_t ws_size,
                              hipStream_t stream)
{
    const int*   premise = (const int*)d_in[0];
    const int*   hyp     = (const int*)d_in[1];
    const float* emb     = (const float*)d_in[2];
    const float* Wih1    = (const float*)d_in[3];
    const float* Whh1    = (const float*)d_in[4];
    const float* bih1    = (const float*)d_in[5];
    const float* bhh1    = (const float*)d_in[6];
    const float* Wih2    = (const float*)d_in[7];
    const float* Whh2    = (const float*)d_in[8];
    const float* bih2    = (const float*)d_in[9];
    const float* bhh2    = (const float*)d_in[10];
    const float* Wy      = (const float*)d_in[11];
    const float* Wh      = (const float*)d_in[12];
    const float* Wr      = (const float*)d_in[13];
    const float* Wt      = (const float*)d_in[14];
    const float* wv      = (const float*)d_in[15];
    const float* fc1w    = (const float*)d_in[16];
    const float* fc1b    = (const float*)d_in[17];
    const float* fc2w    = (const float*)d_in[18];
    const float* fc2b    = (const float*)d_in[19];
    const float* fc3w    = (const float*)d_in[20];
    const float* fc3b    = (const float*)d_in[21];
    float* out = (float*)d_out;

    float* ws = (float*)d_ws;
    size_t off = 0;
    float* xp    = ws + off; off += (size_t)BSZ * PLEN * G4;
    float* xh    = ws + off; off += (size_t)BSZ * HLEN * G4;
    float* outp  = ws + off; off += (size_t)BSZ * PLEN * HDIM;
    float* outhp = ws + off; off += (size_t)BSZ * HLEN * HDIM;
    float* a1t   = ws + off; off += (size_t)BSZ * PLEN * HDIM;
    float* qhb   = ws + off; off += (size_t)BSZ * HLEN * HDIM;
    float* WrtT  = ws + off; off += (size_t)HDIM * 1024;
    float* hAb   = ws + off; off += BSZ * HDIM;
    float* hBb   = ws + off; off += BSZ * HDIM;
    float* rfin  = ws + off; off += BSZ * HDIM;
    unsigned* flagsH = (unsigned*)(ws + off); off += LT * 256;
    if (ws_size < off * sizeof(float)) return;

    // clear flags every call (graph node -> re-cleared on every replay)
    zero_u32<<<dim3(LT), dim3(256), 0, stream>>>(flagsH, LT * 256);

    // input projections (biases folded in)
    proj_kernel<<<dim3(BSZ * PLEN / 16, G4 / 32), dim3(256), 0, stream>>>(
        premise, emb, Wih1, bih1, bhh1, xp);
    proj_kernel<<<dim3(BSZ * HLEN / 16, G4 / 32), dim3(256), 0, stream>>>(
        hyp, emb, Wih2, bih2, bhh2, xh);

    // fused Wr/Wt transpose for the attention GEMV
    wtrans<<<dim3(32, 16), dim3(256), 0, stream>>>(Wr, Wt, WrtT);

    // both LSTMs, persistent, single-writer flag sync
    lstm_coop<<<dim3(256), dim3(256), 0, stream>>>(
        xp, xh, Whh1, Whh2, outp, outhp, hAb, hBb, flagsH);

    // recurrence-free GEMMs: qh[b][t][u] = outh.Wh^T ; a1t[b][p][h] = outp.Wy^T
    gemm16<<<dim3(BSZ * HLEN / 16, HDIM / 16), dim3(256), 0, stream>>>(outhp, Wh, qhb);
    gemm16<<<dim3(BSZ * PLEN / 16, HDIM / 16), dim3(256), 0, stream>>>(outp, Wy, a1t);

    // attention recurrence: fully block-local per batch, zero sync
    att_local<<<dim3(BSZ), dim3(1024), 0, stream>>>(
        a1t, qhb, outp, WrtT, wv, rfin);

    // final classifier
    final_kernel<<<dim3(BSZ), dim3(256), 0, stream>>>(
        rfin, outhp, fc1w, fc1b, fc2w, fc2b, fc3w, fc3b, out);
}